// Round 4
// baseline (116.859 us; speedup 1.0000x reference)
//
#include <hip/hip_runtime.h>

#define HW 16384
#define NB 7
#define NS 7
#define NN 32   // b*f
#define BLK 64                       // one wave per block
#define PPT 4                        // pixels per thread (float4 loads)
#define GRIDX (HW / (BLK * PPT))     // 64
#define NPART (GRIDX * NN)           // 2048 partials

// Four pixels per thread via float4, one wave per block.
// grid = (64, 32) = 2048 blocks = exactly 8 blocks/CU, perfectly balanced.
__global__ __launch_bounds__(BLK, 4) void em_loss_main(
    const float* __restrict__ seg,    // [N, NB, HW]
    const float* __restrict__ masks,  // [N, NS, HW]
    const float* __restrict__ rec,    // [N, NB, 3, HW]
    const float* __restrict__ tgt,    // [N, 3, HW]
    const float* __restrict__ mvis,   // [N, NS, HW]
    const float* __restrict__ ai,     // [N, NS, NB]
    float* __restrict__ partial)      // [NPART]
{
    const int n   = blockIdx.y;
    const int tid = threadIdx.x;
    const int pix = (blockIdx.x * BLK + tid) * PPT;

    __shared__ float s_ai[NS * NB];
    __shared__ float s_A[NB];

    if (tid < NS * NB) s_ai[tid] = ai[n * NS * NB + tid];
    __syncthreads();
    if (tid < NB) {
        float a = 0.0f;
        #pragma unroll
        for (int s = 0; s < NS; ++s) a += s_ai[s * NB + tid];
        s_A[tid] = a;
    }
    __syncthreads();

    const float* seg_n = seg   + (size_t)n * NB * HW + pix;
    const float* rec_n = rec   + (size_t)n * NB * 3 * HW + pix;
    const float* tgt_n = tgt   + (size_t)n * 3 * HW + pix;
    const float* msk_n = masks + (size_t)n * NS * HW + pix;
    const float* mv_n  = mvis  + (size_t)n * NS * HW + pix;

    // --- per-pixel, per-buffer effective weights:
    //     wl[j][b] = sum_s (mask>0.5)*ai,  wd[j][b] = sum_s (mvis>0.5)*ai ---
    float wl[PPT][NB], wd[PPT][NB];
    #pragma unroll
    for (int j = 0; j < PPT; ++j)
        #pragma unroll
        for (int b = 0; b < NB; ++b) { wl[j][b] = 0.0f; wd[j][b] = 0.0f; }

    #pragma unroll
    for (int s = 0; s < NS; ++s) {
        const float4 mk = *reinterpret_cast<const float4*>(msk_n + s * HW);
        const float4 mv = *reinterpret_cast<const float4*>(mv_n + s * HW);
        const float bm[PPT] = { (mk.x > 0.5f) ? 1.0f : 0.0f, (mk.y > 0.5f) ? 1.0f : 0.0f,
                                (mk.z > 0.5f) ? 1.0f : 0.0f, (mk.w > 0.5f) ? 1.0f : 0.0f };
        const float bv[PPT] = { (mv.x > 0.5f) ? 1.0f : 0.0f, (mv.y > 0.5f) ? 1.0f : 0.0f,
                                (mv.z > 0.5f) ? 1.0f : 0.0f, (mv.w > 0.5f) ? 1.0f : 0.0f };
        #pragma unroll
        for (int b = 0; b < NB; ++b) {
            const float a = s_ai[s * NB + b];
            #pragma unroll
            for (int j = 0; j < PPT; ++j) {
                wl[j][b] += bm[j] * a;
                wd[j][b] += bv[j] * a;
            }
        }
    }

    // --- targets (3 channels x 4 pixels) ---
    const float4 t0 = *reinterpret_cast<const float4*>(tgt_n);
    const float4 t1 = *reinterpret_cast<const float4*>(tgt_n + HW);
    const float4 t2 = *reinterpret_cast<const float4*>(tgt_n + 2 * HW);
    const float tr0[PPT] = { t0.x, t0.y, t0.z, t0.w };
    const float tr1[PPT] = { t1.x, t1.y, t1.z, t1.w };
    const float tr2[PPT] = { t2.x, t2.y, t2.z, t2.w };

    // --- single pass over buffers: seg + 3 rec channels each ---
    float acc_bce = 0.0f, acc_mse = 0.0f;
    #pragma unroll
    for (int b = 0; b < NB; ++b) {
        const float4 sv = *reinterpret_cast<const float4*>(seg_n + b * HW);
        const float4 r0 = *reinterpret_cast<const float4*>(rec_n + (b * 3 + 0) * HW);
        const float4 r1 = *reinterpret_cast<const float4*>(rec_n + (b * 3 + 1) * HW);
        const float4 r2 = *reinterpret_cast<const float4*>(rec_n + (b * 3 + 2) * HW);
        const float svv[PPT] = { sv.x, sv.y, sv.z, sv.w };
        const float rv0[PPT] = { r0.x, r0.y, r0.z, r0.w };
        const float rv1[PPT] = { r1.x, r1.y, r1.z, r1.w };
        const float rv2[PPT] = { r2.x, r2.y, r2.z, r2.w };
        const float A = s_A[b];
        #pragma unroll
        for (int j = 0; j < PPT; ++j) {
            const float L1 = fminf(-__logf(svv[j]), 100.0f);
            const float L0 = fminf(-__logf(1.0f - svv[j]), 100.0f);
            acc_bce += A * L0 + wl[j][b] * (L1 - L0);
            const float d0 = rv0[j] - tr0[j];
            const float d1 = rv1[j] - tr1[j];
            const float d2 = rv2[j] - tr2[j];
            acc_mse += wd[j][b] * (d0 * d0 + d1 * d1 + d2 * d2);
        }
    }

    float acc = acc_bce * (1.0f / (float)HW) + 0.1f * acc_mse;

    // --- wave-64 reduction (one wave per block) ---
    #pragma unroll
    for (int off = 32; off > 0; off >>= 1) acc += __shfl_down(acc, off, 64);
    if (tid == 0)
        partial[blockIdx.y * GRIDX + blockIdx.x] = acc;
}

__global__ __launch_bounds__(256) void em_loss_reduce(
    const float* __restrict__ partial, float* __restrict__ out)
{
    __shared__ float s_part[4];
    const int tid = threadIdx.x;
    float a = 0.0f;
    #pragma unroll
    for (int i = 0; i < NPART / 256; ++i) a += partial[i * 256 + tid];
    #pragma unroll
    for (int off = 32; off > 0; off >>= 1) a += __shfl_down(a, off, 64);
    const int wave = tid >> 6;
    const int lane = tid & 63;
    if (lane == 0) s_part[wave] = a;
    __syncthreads();
    if (tid == 0)
        out[0] = (s_part[0] + s_part[1] + s_part[2] + s_part[3]) * (20.0f / 1568.0f);
}

extern "C" void kernel_launch(void* const* d_in, const int* in_sizes, int n_in,
                              void* d_out, int out_size, void* d_ws, size_t ws_size,
                              hipStream_t stream) {
    const float* seg  = (const float*)d_in[0];
    const float* msk  = (const float*)d_in[1];
    const float* rec  = (const float*)d_in[2];
    const float* tgt  = (const float*)d_in[3];
    const float* mvis = (const float*)d_in[4];
    const float* ai   = (const float*)d_in[5];
    float* out     = (float*)d_out;
    float* partial = (float*)d_ws;   // 2048 floats, overwritten every launch

    dim3 grid(GRIDX, NN);
    em_loss_main<<<grid, BLK, 0, stream>>>(seg, msk, rec, tgt, mvis, ai, partial);
    em_loss_reduce<<<1, 256, 0, stream>>>(partial, out);
}